// Round 9
// baseline (483.093 us; speedup 1.0000x reference)
//
#include <hip/hip_runtime.h>
#include <stdint.h>

#define NN 50000
#define NE 600000
#define DD 128
#define MD 64
#define SLICE 6250   // NN/8 nodes per XCD slice

typedef __attribute__((ext_vector_type(8))) short s16x8;
typedef __attribute__((ext_vector_type(4))) float f32x4;

__device__ __forceinline__ float b2f(unsigned int u) {
    union { unsigned int i; float f; } v; v.i = u << 16; return v.f;
}
__device__ __forceinline__ unsigned short f2b(float f) {
    union { float f; unsigned int i; } v; v.f = f;
    unsigned int r = v.i + 0x7fffu + ((v.i >> 16) & 1u);
    return (unsigned short)(r >> 16);
}

// ---------------- zero fill ----------------
__global__ void k_zero2(int* __restrict__ a, int na, int* __restrict__ b, int nb) {
    int i = blockIdx.x * 256 + threadIdx.x;
    if (i < na) a[i] = 0;
    if (i < nb) b[i] = 0;
}

// ---------------- XCD-sliced build with NON-TEMPORAL edge reads ----------------
// nt loads keep the streaming edge arrays out of L2 so the dirty deg/ELL lines
// (~1.7 MB per XCD slice) stay resident and write back once (R8: they were evicted ~7x).
__global__ __launch_bounds__(256)
void k_build(const int* __restrict__ s0, const int* __restrict__ d0,
             const int* __restrict__ s1, const int* __restrict__ d1,
             int* __restrict__ deg,
             unsigned short* __restrict__ ell0, unsigned short* __restrict__ ell1) {
    int slice = blockIdx.x & 7;
    int chunk = blockIdx.x >> 3;          // 640 chunks of 938 edges
    int lo = slice * SLICE;
    int base = chunk * 938;
    int end = base + 938; if (end > NE) end = NE;
    for (int e = base + threadIdx.x; e < end; e += 256) {
        int a = __builtin_nontemporal_load(s0 + e);
        int b = __builtin_nontemporal_load(d0 + e);
        int c = __builtin_nontemporal_load(s1 + e);
        int d = __builtin_nontemporal_load(d1 + e);
        if ((unsigned)(a - lo) < SLICE) atomicAdd(&deg[a], 1);
        if ((unsigned)(c - lo) < SLICE) atomicAdd(&deg[2 * NN + c], 1);
        if ((unsigned)(b - lo) < SLICE) {
            int p0 = atomicAdd(&deg[NN + b], 1);
            if (p0 < MD) ell0[b * MD + p0] = (unsigned short)a;
        }
        if ((unsigned)(d - lo) < SLICE) {
            int p1 = atomicAdd(&deg[3 * NN + d], 1);
            if (p1 < MD) ell1[d * MD + p1] = (unsigned short)c;
        }
    }
}

// ---------------- scale+cast: fp32 x * rsqrt(dout) -> bf16 table ----------------
__global__ void k_scale_cast(const float* __restrict__ xA, const float* __restrict__ xB,
                             const int* __restrict__ deg,
                             unsigned short* __restrict__ oA, unsigned short* __restrict__ oB) {
    int idx2 = blockIdx.x * 256 + threadIdx.x;      // float2 units
    if (idx2 >= NN * 64) return;
    const float* x = blockIdx.y ? xB : xA;
    const int* dg = blockIdx.y ? (deg + 2 * NN) : deg;
    unsigned short* o = blockIdx.y ? oB : oA;
    float2 v = ((const float2*)x)[idx2];
    float sc = rsqrtf(fmaxf((float)dg[idx2 >> 6], 1.0f));
    ((unsigned int*)o)[idx2] = (unsigned int)f2b(v.x * sc) | ((unsigned int)f2b(v.y * sc) << 16);
}

// ---------------- weight prep: fp32 [K][128] -> bf16 [128][K] (transposed) ----------------
__global__ void k_prepw(const float* __restrict__ W1r0, const float* __restrict__ W1r1,
                        const float* __restrict__ W2r0, const float* __restrict__ W2r1,
                        const float* __restrict__ Wm1, unsigned short* __restrict__ wt) {
    int which = blockIdx.y;
    const float* W; unsigned short* Wt; int K;
    if (which == 0)      { W = W1r0; Wt = wt;         K = 128; }
    else if (which == 1) { W = W1r1; Wt = wt + 16384; K = 128; }
    else if (which == 2) { W = W2r0; Wt = wt + 32768; K = 128; }
    else if (which == 3) { W = W2r1; Wt = wt + 49152; K = 128; }
    else                 { W = Wm1;  Wt = wt + 65536; K = 256; }
    int t = blockIdx.x * 256 + threadIdx.x;
    if (t >= K * 128) return;
    int k = t >> 7, j = t & 127;
    Wt[(size_t)j * K + k] = f2b(W[t]);
}

// ---------------- aggregation, batched over 2 relations (blockIdx.y) ----------------
__global__ __launch_bounds__(256)
void k_agg2(const unsigned short* __restrict__ t0, const unsigned short* __restrict__ t1,
            const unsigned short* __restrict__ e0p, const unsigned short* __restrict__ e1p,
            const int* __restrict__ dn0, const int* __restrict__ dn1,
            unsigned short* __restrict__ o0, unsigned short* __restrict__ o1) {
    const unsigned short* table = blockIdx.y ? t1 : t0;
    const unsigned short* ell   = blockIdx.y ? e1p : e0p;
    const int* din              = blockIdx.y ? dn1 : dn0;
    unsigned short* out         = blockIdx.y ? o1 : o0;

    int tid = threadIdx.x;
    int lane = tid & 63;
    int hl = lane & 31;
    int base = lane & 32;
    int node = blockIdx.x * 8 + (tid >> 5);

    int dtrue = din[node];
    int d = (dtrue < 0) ? 0 : ((dtrue > MD) ? MD : dtrue);
    const unsigned short* el = ell + (size_t)node * MD;
    int eA = (hl < d) ? (int)el[hl] : 0;
    int eB = (32 + hl < d) ? (int)el[32 + hl] : 0;

    float a0 = 0.f, a1 = 0.f, a2 = 0.f, a3 = 0.f;
    int dm = (d < 32) ? d : 32;
    int i = 0;
    for (; i + 4 <= dm; i += 4) {
        int ea = __shfl(eA, base + i, 64);
        int eb = __shfl(eA, base + i + 1, 64);
        int ec = __shfl(eA, base + i + 2, 64);
        int ed = __shfl(eA, base + i + 3, 64);
        uint2 u0 = *(const uint2*)(table + (size_t)ea * DD + hl * 4);
        uint2 u1 = *(const uint2*)(table + (size_t)eb * DD + hl * 4);
        uint2 u2 = *(const uint2*)(table + (size_t)ec * DD + hl * 4);
        uint2 u3 = *(const uint2*)(table + (size_t)ed * DD + hl * 4);
        a0 += b2f(u0.x & 0xffffu) + b2f(u1.x & 0xffffu) + b2f(u2.x & 0xffffu) + b2f(u3.x & 0xffffu);
        a1 += b2f(u0.x >> 16)     + b2f(u1.x >> 16)     + b2f(u2.x >> 16)     + b2f(u3.x >> 16);
        a2 += b2f(u0.y & 0xffffu) + b2f(u1.y & 0xffffu) + b2f(u2.y & 0xffffu) + b2f(u3.y & 0xffffu);
        a3 += b2f(u0.y >> 16)     + b2f(u1.y >> 16)     + b2f(u2.y >> 16)     + b2f(u3.y >> 16);
    }
    for (; i < dm; ++i) {
        int ea = __shfl(eA, base + i, 64);
        uint2 u0 = *(const uint2*)(table + (size_t)ea * DD + hl * 4);
        a0 += b2f(u0.x & 0xffffu); a1 += b2f(u0.x >> 16);
        a2 += b2f(u0.y & 0xffffu); a3 += b2f(u0.y >> 16);
    }
    if (d > 32) {
        for (int j = 32; j < d; ++j) {
            int ea = __shfl(eB, base + j - 32, 64);
            uint2 u0 = *(const uint2*)(table + (size_t)ea * DD + hl * 4);
            a0 += b2f(u0.x & 0xffffu); a1 += b2f(u0.x >> 16);
            a2 += b2f(u0.y & 0xffffu); a3 += b2f(u0.y >> 16);
        }
    }
    float sc = rsqrtf(fmaxf((float)dtrue, 1.0f));
    uint2 o;
    o.x = (unsigned int)f2b(a0 * sc) | ((unsigned int)f2b(a1 * sc) << 16);
    o.y = (unsigned int)f2b(a2 * sc) | ((unsigned int)f2b(a3 * sc) << 16);
    *(uint2*)(out + (size_t)node * DD + hl * 4) = o;
}

// ---------------- MFMA GEMM, batched over 2 problems (conv1) ----------------
template<int RELU, int BIAS, int PS>
__global__ __launch_bounds__(256)
void k_gemm2(const unsigned short* __restrict__ A0, const unsigned short* __restrict__ A1,
             const unsigned short* __restrict__ Wt0, const unsigned short* __restrict__ Wt1,
             const float* __restrict__ bias0, const float* __restrict__ bias1,
             const int* __restrict__ ps0, const int* __restrict__ ps1,
             unsigned short* __restrict__ out0, unsigned short* __restrict__ out1,
             int ldo, int oc0, int oc1) {
    const unsigned short* A  = blockIdx.y ? A1 : A0;
    const unsigned short* Wt = blockIdx.y ? Wt1 : Wt0;
    const float* bias        = blockIdx.y ? bias1 : bias0;
    const int* psdeg         = blockIdx.y ? ps1 : ps0;
    unsigned short* out      = blockIdx.y ? out1 : out0;
    int ocol                 = blockIdx.y ? oc1 : oc0;

    __shared__ __align__(16) unsigned short Ad[64 * 128];
    __shared__ __align__(16) unsigned short Wl[128 * 128];
    int tid = threadIdx.x;
    int row0 = blockIdx.x * 64;
    int lane = tid & 63, w = tid >> 6, m = lane & 15, q = lane >> 4;
    f32x4 acc[8];
#pragma unroll
    for (int c = 0; c < 8; ++c) acc[c] = (f32x4){0.f, 0.f, 0.f, 0.f};
#pragma unroll
    for (int i = 0; i < 4; ++i) {
        int c = tid + i * 256;
        int r = c >> 4, c8 = c & 15;
        uint4 v = make_uint4(0u, 0u, 0u, 0u);
        if (row0 + r < NN) v = *(const uint4*)(A + (size_t)(row0 + r) * 128 + c8 * 8);
        *(uint4*)(Ad + r * 128 + c8 * 8) = v;
    }
#pragma unroll
    for (int i = 0; i < 8; ++i) {
        int c = tid + i * 256;
        *(uint4*)(Wl + c * 8) = *(const uint4*)(Wt + c * 8);
    }
    __syncthreads();
#pragma unroll
    for (int kt = 0; kt < 4; ++kt) {
        s16x8 a = *(const s16x8*)(Ad + (w * 16 + m) * 128 + kt * 32 + q * 8);
#pragma unroll
        for (int c = 0; c < 8; ++c) {
            s16x8 b = *(const s16x8*)(Wl + (c * 16 + m) * 128 + kt * 32 + q * 8);
            acc[c] = __builtin_amdgcn_mfma_f32_16x16x32_bf16(a, b, acc[c], 0, 0, 0);
        }
    }
#pragma unroll
    for (int c = 0; c < 8; ++c) {
        int col = c * 16 + m;
        float bv = BIAS ? bias[col] : 0.f;
#pragma unroll
        for (int r = 0; r < 4; ++r) {
            int row = row0 + w * 16 + q * 4 + r;
            if (row < NN) {
                float v = acc[c][r] + bv;
                if (RELU) v = fmaxf(v, 0.f);
                if (PS) v *= rsqrtf(fmaxf((float)psdeg[row], 1.0f));
                out[(size_t)row * ldo + ocol + col] = f2b(v);
            }
        }
    }
}

// ---------------- fused conv2-GEMMs + MLP GEMM: h1 = (ag0@W2r0+b0)@Wm1hi + (ag1@W2r1+b1)@Wm1lo ----
// P tiles never hit global memory (h2 not materialized) — LDS roundtrip for C->A layout.
__global__ __launch_bounds__(256)
void k_fuse3(const unsigned short* __restrict__ ag0, const unsigned short* __restrict__ ag1,
             const unsigned short* __restrict__ w2r0t, const unsigned short* __restrict__ w2r1t,
             const float* __restrict__ b2r0, const float* __restrict__ b2r1,
             const unsigned short* __restrict__ wm1t,   // [128 j][256 k] transposed
             unsigned short* __restrict__ h1) {
    __shared__ __align__(16) unsigned short Ad[64 * 128];
    __shared__ __align__(16) unsigned short Wl[128 * 128];
    int tid = threadIdx.x, lane = tid & 63, w = tid >> 6, m = lane & 15, q = lane >> 4;
    int row0 = blockIdx.x * 64;
    f32x4 acc[8];
#pragma unroll
    for (int c = 0; c < 8; ++c) acc[c] = (f32x4){0.f, 0.f, 0.f, 0.f};

    for (int rel = 0; rel < 2; ++rel) {
        const unsigned short* A  = rel ? ag1 : ag0;
        const unsigned short* W2 = rel ? w2r1t : w2r0t;
        const float* bias        = rel ? b2r1 : b2r0;
        int koff                 = rel ? 0 : 128;   // h2B (ag0) occupies cols[128:256) -> Wm1 rows 128..
        // stage ag tile + W2 panel
#pragma unroll
        for (int i = 0; i < 4; ++i) {
            int c = tid + i * 256;
            int r = c >> 4, c8 = c & 15;
            uint4 v = make_uint4(0u, 0u, 0u, 0u);
            if (row0 + r < NN) v = *(const uint4*)(A + (size_t)(row0 + r) * 128 + c8 * 8);
            *(uint4*)(Ad + r * 128 + c8 * 8) = v;
        }
#pragma unroll
        for (int i = 0; i < 8; ++i) {
            int c = tid + i * 256;
            *(uint4*)(Wl + c * 8) = *(const uint4*)(W2 + c * 8);
        }
        __syncthreads();
        // pass 1: P = ag @ W2
        f32x4 p[8];
#pragma unroll
        for (int c = 0; c < 8; ++c) p[c] = (f32x4){0.f, 0.f, 0.f, 0.f};
#pragma unroll
        for (int kt = 0; kt < 4; ++kt) {
            s16x8 a = *(const s16x8*)(Ad + (w * 16 + m) * 128 + kt * 32 + q * 8);
#pragma unroll
            for (int c = 0; c < 8; ++c) {
                s16x8 b = *(const s16x8*)(Wl + (c * 16 + m) * 128 + kt * 32 + q * 8);
                p[c] = __builtin_amdgcn_mfma_f32_16x16x32_bf16(a, b, p[c], 0, 0, 0);
            }
        }
        __syncthreads();   // all Ad/Wl reads done before overwrite
        // P+bias -> bf16 -> Ad (row-major = A-operand layout)
#pragma unroll
        for (int c = 0; c < 8; ++c) {
            int col = c * 16 + m;
            float bv = bias[col];
#pragma unroll
            for (int r = 0; r < 4; ++r)
                Ad[(w * 16 + q * 4 + r) * 128 + col] = f2b(p[c][r] + bv);
        }
        // stage Wm1 half-panel: Wl[j][k] = wm1t[j][koff+k]
#pragma unroll
        for (int i = 0; i < 8; ++i) {
            int c = tid + i * 256;
            int j = c >> 4, k8 = c & 15;
            *(uint4*)(Wl + j * 128 + k8 * 8) = *(const uint4*)(wm1t + (size_t)j * 256 + koff + k8 * 8);
        }
        __syncthreads();
        // pass 2: acc += P @ Wm1half
#pragma unroll
        for (int kt = 0; kt < 4; ++kt) {
            s16x8 a = *(const s16x8*)(Ad + (w * 16 + m) * 128 + kt * 32 + q * 8);
#pragma unroll
            for (int c = 0; c < 8; ++c) {
                s16x8 b = *(const s16x8*)(Wl + (c * 16 + m) * 128 + kt * 32 + q * 8);
                acc[c] = __builtin_amdgcn_mfma_f32_16x16x32_bf16(a, b, acc[c], 0, 0, 0);
            }
        }
        __syncthreads();   // before next rel restages
    }
#pragma unroll
    for (int c = 0; c < 8; ++c) {
        int col = c * 16 + m;
#pragma unroll
        for (int r = 0; r < 4; ++r) {
            int row = row0 + w * 16 + q * 4 + r;
            if (row < NN) h1[(size_t)row * DD + col] = f2b(acc[c][r]);
        }
    }
}

// ---------------- BN statistics ----------------
__global__ void k_bnstats(const unsigned short* __restrict__ h1, float* __restrict__ sums) {
    int col = threadIdx.x & 127;
    int half = threadIdx.x >> 7;
    int r0 = blockIdx.x * 500;
    float s = 0.f, s2 = 0.f;
    for (int r = r0 + half; r < r0 + 500; r += 2) {
        float v = b2f((unsigned int)h1[(size_t)r * DD + col]);
        s += v; s2 += v * v;
    }
    __shared__ float ls[256], ls2[256];
    ls[threadIdx.x] = s; ls2[threadIdx.x] = s2;
    __syncthreads();
    if (half == 0) {
        atomicAdd(&sums[col], ls[col] + ls[col + 128]);
        atomicAdd(&sums[col + 128], ls2[col] + ls2[col + 128]);
    }
}

__global__ void k_bnfinal(const float* __restrict__ sums,
                          const float* __restrict__ gamma, const float* __restrict__ beta,
                          float* __restrict__ bn) {
    int c = threadIdx.x;
    if (c >= 128) return;
    const float inv = 1.0f / (float)NN;
    float mu = sums[c] * inv;
    float var = sums[c + 128] * inv - mu * mu;
    float a = gamma[c] * rsqrtf(var + 1e-5f);
    bn[c] = a;
    bn[c + 128] = beta[c] - mu * a;
}

// ---------------- head: out fp32 ----------------
__global__ void k_head(const unsigned short* __restrict__ h1, const float* __restrict__ bn,
                       const float* __restrict__ Wm2, float* __restrict__ out) {
    int row = blockIdx.x * 4 + (threadIdx.x >> 6);
    int lane = threadIdx.x & 63;
    if (row >= NN) return;
    float h0 = b2f((unsigned int)h1[(size_t)row * DD + lane]);
    float h64 = b2f((unsigned int)h1[(size_t)row * DD + lane + 64]);
    float v0 = fmaxf(h0 * bn[lane] + bn[128 + lane], 0.f);
    float v1 = fmaxf(h64 * bn[lane + 64] + bn[128 + lane + 64], 0.f);
    float2 wa = *(const float2*)(Wm2 + lane * 2);
    float2 wb = *(const float2*)(Wm2 + (lane + 64) * 2);
    float acc0 = v0 * wa.x + v1 * wb.x;
    float acc1 = v0 * wa.y + v1 * wb.y;
#pragma unroll
    for (int off = 32; off > 0; off >>= 1) {
        acc0 += __shfl_down(acc0, off, 64);
        acc1 += __shfl_down(acc1, off, 64);
    }
    if (lane == 0) *(float2*)(out + (size_t)row * 2) = make_float2(acc0, acc1);
}

// ---------------- canary ----------------
__global__ void k_check(const int* __restrict__ deg, const unsigned short* __restrict__ hB,
                        const unsigned short* __restrict__ h1,
                        float* __restrict__ out, int hostFail) {
    if (threadIdx.x != 0 || blockIdx.x != 0) return;
    float sentinel = 0.f;
    if (hostFail) sentinel = (float)hostFail;
    else {
        int d = deg[NN + 1234];
        if (d < 0 || d > 100000) sentinel = 100.0f;
        else {
            float sa = 0.f;
            for (int j = 0; j < DD; ++j) sa += fabsf(b2f((unsigned int)hB[777 * DD + j]));
            if (!(sa > 0.f)) sentinel = 200.0f;
            else {
                float sc = 0.f;
                for (int j = 0; j < DD; ++j) sc += fabsf(b2f((unsigned int)h1[(size_t)444 * DD + j]));
                if (!(sc > 0.f)) sentinel = 400.0f;
            }
        }
    }
    if (sentinel != 0.f) out[0] = sentinel;
}

// ---------------- workspace layout (bytes) ----------------
// h1 overlays the ELL region (ells dead after the conv2 agg2, before k_fuse3).
static constexpr size_t O_DEG  = 0;           // 800000
static constexpr size_t O_ELL0 = 800000;      // 6.4M -> 7200000
static constexpr size_t O_ELL1 = 7200000;     // -> 13600000
static constexpr size_t O_H1   = 800000;      // 12.8M overlay (ells dead at fuse3)
static constexpr size_t O_XAS  = 13600000;    // 12.8M ; hA overlays
static constexpr size_t O_XBS  = 26400000;    // 12.8M ; hB overlays
static constexpr size_t O_AG0  = 39200000;    // 12.8M
static constexpr size_t O_AG1  = 52000000;    // 12.8M
static constexpr size_t O_WT   = 64800000;    // 196608
static constexpr size_t O_BNS  = 64996608;    // 1024
static constexpr size_t O_BNAB = 64997632;    // 1024
static constexpr size_t O_END  = 64998656;

extern "C" void kernel_launch(void* const* d_in, const int* in_sizes, int n_in,
                              void* d_out, int out_size, void* d_ws, size_t ws_size,
                              hipStream_t stream) {
    const float* xA    = (const float*)d_in[0];
    const float* xB    = (const float*)d_in[1];
    const int* src0 = (const int*)d_in[2];
    const int* dst0 = (const int*)d_in[3];
    const int* src1 = (const int*)d_in[4];
    const int* dst1 = (const int*)d_in[5];
    const float* W1r0  = (const float*)d_in[6];
    const float* b1r0  = (const float*)d_in[7];
    const float* W1r1  = (const float*)d_in[8];
    const float* b1r1  = (const float*)d_in[9];
    const float* W2r0  = (const float*)d_in[10];
    const float* b2r0  = (const float*)d_in[11];
    const float* W2r1  = (const float*)d_in[12];
    const float* b2r1  = (const float*)d_in[13];
    const float* Wm1   = (const float*)d_in[14];
    const float* gamma = (const float*)d_in[15];
    const float* beta  = (const float*)d_in[16];
    const float* Wm2   = (const float*)d_in[17];

    char* ws = (char*)d_ws;
    int*   deg  = (int*)(ws + O_DEG);
    unsigned short* ell0 = (unsigned short*)(ws + O_ELL0);
    unsigned short* ell1 = (unsigned short*)(ws + O_ELL1);
    unsigned short* h1  = (unsigned short*)(ws + O_H1);    // overlay of ells
    unsigned short* xAs = (unsigned short*)(ws + O_XAS);
    unsigned short* hA  = (unsigned short*)(ws + O_XAS);   // overlay
    unsigned short* xBs = (unsigned short*)(ws + O_XBS);
    unsigned short* hB  = (unsigned short*)(ws + O_XBS);   // overlay
    unsigned short* ag0 = (unsigned short*)(ws + O_AG0);
    unsigned short* ag1 = (unsigned short*)(ws + O_AG1);
    unsigned short* wt  = (unsigned short*)(ws + O_WT);
    float* bns  = (float*)(ws + O_BNS);
    float* bnab = (float*)(ws + O_BNAB);
    float* out  = (float*)d_out;

    int hostFail = 0;
    if (ws_size < O_END) hostFail = 700;
    else if (n_in < 18) hostFail = 900;
    else if (in_sizes[0] != NN * DD) hostFail = 800;
    else if (in_sizes[2] != NE) hostFail = 850;

    if (!hostFail) {
        k_zero2<<<(200000 + 255) / 256, 256, 0, stream>>>(deg, 200000, (int*)bns, 256);

        k_build<<<8 * 640, 256, 0, stream>>>(src0, dst0, src1, dst1, deg, ell0, ell1);
        k_scale_cast<<<dim3(12500, 2), 256, 0, stream>>>(xA, xB, deg, xAs, xBs);
        k_prepw<<<dim3(128, 5), 256, 0, stream>>>(W1r0, W1r1, W2r0, W2r1, Wm1, wt);

        const int AB = 6250;              // 8 nodes/block
        const int GB = (NN + 63) / 64;    // 782

        // conv1 aggs + gemms
        k_agg2<<<dim3(AB, 2), 256, 0, stream>>>(xAs, xBs, ell0, ell1, deg + NN, deg + 3 * NN, ag0, ag1);
        k_gemm2<1,1,1><<<dim3(GB, 2), 256, 0, stream>>>(ag0, ag1, wt, wt + 16384, b1r0, b1r1,
                                                        deg + 2 * NN, deg, hB, hA, 128, 0, 0);
        // conv2 aggs (ells die here)
        k_agg2<<<dim3(AB, 2), 256, 0, stream>>>(hA, hB, ell0, ell1, deg + NN, deg + 3 * NN, ag0, ag1);
        // fused conv2 gemms + MLP -> h1 (h2 never materialized)
        k_fuse3<<<GB, 256, 0, stream>>>(ag0, ag1, wt + 32768, wt + 49152, b2r0, b2r1,
                                        wt + 65536, h1);

        k_bnstats<<<100, 256, 0, stream>>>(h1, bns);
        k_bnfinal<<<1, 128, 0, stream>>>(bns, gamma, beta, bnab);
        k_head<<<12500, 256, 0, stream>>>(h1, bnab, Wm2, out);
    }
    k_check<<<1, 64, 0, stream>>>(deg, hB, h1, out, hostFail);
}

// Round 10
// 395.169 us; speedup vs baseline: 1.2225x; 1.2225x over previous
//
#include <hip/hip_runtime.h>
#include <stdint.h>

#define NN 50000
#define NE 600000
#define DD 128
#define MD 64
#define SLICE 6250   // NN/8 nodes per XCD slice

typedef __attribute__((ext_vector_type(8))) short s16x8;
typedef __attribute__((ext_vector_type(4))) float f32x4;

__device__ __forceinline__ float b2f(unsigned int u) {
    union { unsigned int i; float f; } v; v.i = u << 16; return v.f;
}
__device__ __forceinline__ unsigned short f2b(float f) {
    union { float f; unsigned int i; } v; v.f = f;
    unsigned int r = v.i + 0x7fffu + ((v.i >> 16) & 1u);
    return (unsigned short)(r >> 16);
}

// ---------------- zero fill (deg + bn sum copies) ----------------
__global__ void k_zero2(int* __restrict__ a, int na, int* __restrict__ b, int nb) {
    int i = blockIdx.x * 256 + threadIdx.x;
    if (i < na) a[i] = 0;
    if (i < nb) b[i] = 0;
}

// ---------------- XCD-sliced build (plain loads — nt regressed in R9) ----------------
__global__ __launch_bounds__(256)
void k_build(const int* __restrict__ s0, const int* __restrict__ d0,
             const int* __restrict__ s1, const int* __restrict__ d1,
             int* __restrict__ deg,
             unsigned short* __restrict__ ell0, unsigned short* __restrict__ ell1) {
    int slice = blockIdx.x & 7;
    int chunk = blockIdx.x >> 3;          // 640 chunks of 938 edges
    int lo = slice * SLICE;
    int base = chunk * 938;
    int end = base + 938; if (end > NE) end = NE;
    for (int e = base + threadIdx.x; e < end; e += 256) {
        int a = s0[e], b = d0[e], c = s1[e], d = d1[e];
        if ((unsigned)(a - lo) < SLICE) atomicAdd(&deg[a], 1);
        if ((unsigned)(c - lo) < SLICE) atomicAdd(&deg[2 * NN + c], 1);
        if ((unsigned)(b - lo) < SLICE) {
            int p0 = atomicAdd(&deg[NN + b], 1);
            if (p0 < MD) ell0[b * MD + p0] = (unsigned short)a;
        }
        if ((unsigned)(d - lo) < SLICE) {
            int p1 = atomicAdd(&deg[3 * NN + d], 1);
            if (p1 < MD) ell1[d * MD + p1] = (unsigned short)c;
        }
    }
}

// ---------------- merged prep: scale-cast both inputs + transpose/cast 5 weights ----------------
// blocks [0,12500): xA  [12500,25000): xB  [25000,25384): weights (98304 elems)
__global__ void k_prep(const float* __restrict__ xA, const float* __restrict__ xB,
                       const int* __restrict__ deg,
                       unsigned short* __restrict__ oA, unsigned short* __restrict__ oB,
                       const float* __restrict__ W1r0, const float* __restrict__ W1r1,
                       const float* __restrict__ W2r0, const float* __restrict__ W2r1,
                       const float* __restrict__ Wm1, unsigned short* __restrict__ wt) {
    int bx = blockIdx.x;
    if (bx < 25000) {
        int half = (bx >= 12500);
        int idx2 = (bx - half * 12500) * 256 + threadIdx.x;   // float2 units
        const float* x = half ? xB : xA;
        const int* dg = half ? (deg + 2 * NN) : deg;
        unsigned short* o = half ? oB : oA;
        float2 v = ((const float2*)x)[idx2];
        float sc = rsqrtf(fmaxf((float)dg[idx2 >> 6], 1.0f));
        ((unsigned int*)o)[idx2] = (unsigned int)f2b(v.x * sc) | ((unsigned int)f2b(v.y * sc) << 16);
    } else {
        int t = (bx - 25000) * 256 + threadIdx.x;             // 0..98303
        if (t >= 98304) return;
        if (t < 65536) {
            int which = t >> 14, local = t & 16383;
            const float* W = (which == 0) ? W1r0 : (which == 1) ? W1r1 : (which == 2) ? W2r0 : W2r1;
            int k = local >> 7, j = local & 127;
            wt[which * 16384 + j * 128 + k] = f2b(W[local]);
        } else {
            int local = t - 65536;                            // Wm1: [256 k][128 j]
            int k = local >> 7, j = local & 127;
            wt[65536 + j * 256 + k] = f2b(Wm1[local]);
        }
    }
}

// ---------------- aggregation, batched over 2 relations (blockIdx.y) ----------------
__global__ __launch_bounds__(256)
void k_agg2(const unsigned short* __restrict__ t0, const unsigned short* __restrict__ t1,
            const unsigned short* __restrict__ e0p, const unsigned short* __restrict__ e1p,
            const int* __restrict__ dn0, const int* __restrict__ dn1,
            unsigned short* __restrict__ o0, unsigned short* __restrict__ o1) {
    const unsigned short* table = blockIdx.y ? t1 : t0;
    const unsigned short* ell   = blockIdx.y ? e1p : e0p;
    const int* din              = blockIdx.y ? dn1 : dn0;
    unsigned short* out         = blockIdx.y ? o1 : o0;

    int tid = threadIdx.x;
    int lane = tid & 63;
    int hl = lane & 31;
    int base = lane & 32;
    int node = blockIdx.x * 8 + (tid >> 5);

    int dtrue = din[node];
    int d = (dtrue < 0) ? 0 : ((dtrue > MD) ? MD : dtrue);
    const unsigned short* el = ell + (size_t)node * MD;
    int eA = (hl < d) ? (int)el[hl] : 0;
    int eB = (32 + hl < d) ? (int)el[32 + hl] : 0;

    float a0 = 0.f, a1 = 0.f, a2 = 0.f, a3 = 0.f;
    int dm = (d < 32) ? d : 32;
    int i = 0;
    for (; i + 4 <= dm; i += 4) {
        int ea = __shfl(eA, base + i, 64);
        int eb = __shfl(eA, base + i + 1, 64);
        int ec = __shfl(eA, base + i + 2, 64);
        int ed = __shfl(eA, base + i + 3, 64);
        uint2 u0 = *(const uint2*)(table + (size_t)ea * DD + hl * 4);
        uint2 u1 = *(const uint2*)(table + (size_t)eb * DD + hl * 4);
        uint2 u2 = *(const uint2*)(table + (size_t)ec * DD + hl * 4);
        uint2 u3 = *(const uint2*)(table + (size_t)ed * DD + hl * 4);
        a0 += b2f(u0.x & 0xffffu) + b2f(u1.x & 0xffffu) + b2f(u2.x & 0xffffu) + b2f(u3.x & 0xffffu);
        a1 += b2f(u0.x >> 16)     + b2f(u1.x >> 16)     + b2f(u2.x >> 16)     + b2f(u3.x >> 16);
        a2 += b2f(u0.y & 0xffffu) + b2f(u1.y & 0xffffu) + b2f(u2.y & 0xffffu) + b2f(u3.y & 0xffffu);
        a3 += b2f(u0.y >> 16)     + b2f(u1.y >> 16)     + b2f(u2.y >> 16)     + b2f(u3.y >> 16);
    }
    for (; i < dm; ++i) {
        int ea = __shfl(eA, base + i, 64);
        uint2 u0 = *(const uint2*)(table + (size_t)ea * DD + hl * 4);
        a0 += b2f(u0.x & 0xffffu); a1 += b2f(u0.x >> 16);
        a2 += b2f(u0.y & 0xffffu); a3 += b2f(u0.y >> 16);
    }
    if (d > 32) {
        for (int j = 32; j < d; ++j) {
            int ea = __shfl(eB, base + j - 32, 64);
            uint2 u0 = *(const uint2*)(table + (size_t)ea * DD + hl * 4);
            a0 += b2f(u0.x & 0xffffu); a1 += b2f(u0.x >> 16);
            a2 += b2f(u0.y & 0xffffu); a3 += b2f(u0.y >> 16);
        }
    }
    float sc = rsqrtf(fmaxf((float)dtrue, 1.0f));
    uint2 o;
    o.x = (unsigned int)f2b(a0 * sc) | ((unsigned int)f2b(a1 * sc) << 16);
    o.y = (unsigned int)f2b(a2 * sc) | ((unsigned int)f2b(a3 * sc) << 16);
    *(uint2*)(out + (size_t)node * DD + hl * 4) = o;
}

// ---------------- MFMA GEMM, batched over 2 problems (conv1) ----------------
template<int RELU, int BIAS, int PS>
__global__ __launch_bounds__(256)
void k_gemm2(const unsigned short* __restrict__ A0, const unsigned short* __restrict__ A1,
             const unsigned short* __restrict__ Wt0, const unsigned short* __restrict__ Wt1,
             const float* __restrict__ bias0, const float* __restrict__ bias1,
             const int* __restrict__ ps0, const int* __restrict__ ps1,
             unsigned short* __restrict__ out0, unsigned short* __restrict__ out1,
             int ldo, int oc0, int oc1) {
    const unsigned short* A  = blockIdx.y ? A1 : A0;
    const unsigned short* Wt = blockIdx.y ? Wt1 : Wt0;
    const float* bias        = blockIdx.y ? bias1 : bias0;
    const int* psdeg         = blockIdx.y ? ps1 : ps0;
    unsigned short* out      = blockIdx.y ? out1 : out0;
    int ocol                 = blockIdx.y ? oc1 : oc0;

    __shared__ __align__(16) unsigned short Ad[64 * 128];
    __shared__ __align__(16) unsigned short Wl[128 * 128];
    int tid = threadIdx.x;
    int row0 = blockIdx.x * 64;
    int lane = tid & 63, w = tid >> 6, m = lane & 15, q = lane >> 4;
    f32x4 acc[8];
#pragma unroll
    for (int c = 0; c < 8; ++c) acc[c] = (f32x4){0.f, 0.f, 0.f, 0.f};
#pragma unroll
    for (int i = 0; i < 4; ++i) {
        int c = tid + i * 256;
        int r = c >> 4, c8 = c & 15;
        uint4 v = make_uint4(0u, 0u, 0u, 0u);
        if (row0 + r < NN) v = *(const uint4*)(A + (size_t)(row0 + r) * 128 + c8 * 8);
        *(uint4*)(Ad + r * 128 + c8 * 8) = v;
    }
#pragma unroll
    for (int i = 0; i < 8; ++i) {
        int c = tid + i * 256;
        *(uint4*)(Wl + c * 8) = *(const uint4*)(Wt + c * 8);
    }
    __syncthreads();
#pragma unroll
    for (int kt = 0; kt < 4; ++kt) {
        s16x8 a = *(const s16x8*)(Ad + (w * 16 + m) * 128 + kt * 32 + q * 8);
#pragma unroll
        for (int c = 0; c < 8; ++c) {
            s16x8 b = *(const s16x8*)(Wl + (c * 16 + m) * 128 + kt * 32 + q * 8);
            acc[c] = __builtin_amdgcn_mfma_f32_16x16x32_bf16(a, b, acc[c], 0, 0, 0);
        }
    }
#pragma unroll
    for (int c = 0; c < 8; ++c) {
        int col = c * 16 + m;
        float bv = BIAS ? bias[col] : 0.f;
#pragma unroll
        for (int r = 0; r < 4; ++r) {
            int row = row0 + w * 16 + q * 4 + r;
            if (row < NN) {
                float v = acc[c][r] + bv;
                if (RELU) v = fmaxf(v, 0.f);
                if (PS) v *= rsqrtf(fmaxf((float)psdeg[row], 1.0f));
                out[(size_t)row * ldo + ocol + col] = f2b(v);
            }
        }
    }
}

// ---------------- fused conv2 GEMMs + MLP GEMM + BN partial stats ----------------
// h1 = (ag0@W2r0+b0)@Wm1[128:] + (ag1@W2r1+b1)@Wm1[:128]; h2 never materialized.
// Epilogue: per-block column sums/sumsqs of rounded h1 -> atomicAdd into 8 spread copies.
__global__ __launch_bounds__(256)
void k_fuse3(const unsigned short* __restrict__ ag0, const unsigned short* __restrict__ ag1,
             const unsigned short* __restrict__ w2r0t, const unsigned short* __restrict__ w2r1t,
             const float* __restrict__ b2r0, const float* __restrict__ b2r1,
             const unsigned short* __restrict__ wm1t,   // [128 j][256 k]
             unsigned short* __restrict__ h1, float* __restrict__ bns) {
    __shared__ __align__(16) unsigned short Ad[64 * 128];
    __shared__ __align__(16) unsigned short Wl[128 * 128];
    int tid = threadIdx.x, lane = tid & 63, w = tid >> 6, m = lane & 15, q = lane >> 4;
    int row0 = blockIdx.x * 64;
    f32x4 acc[8];
#pragma unroll
    for (int c = 0; c < 8; ++c) acc[c] = (f32x4){0.f, 0.f, 0.f, 0.f};

    for (int rel = 0; rel < 2; ++rel) {
        const unsigned short* A  = rel ? ag1 : ag0;
        const unsigned short* W2 = rel ? w2r1t : w2r0t;
        const float* bias        = rel ? b2r1 : b2r0;
        int koff                 = rel ? 0 : 128;
#pragma unroll
        for (int i = 0; i < 4; ++i) {
            int c = tid + i * 256;
            int r = c >> 4, c8 = c & 15;
            uint4 v = make_uint4(0u, 0u, 0u, 0u);
            if (row0 + r < NN) v = *(const uint4*)(A + (size_t)(row0 + r) * 128 + c8 * 8);
            *(uint4*)(Ad + r * 128 + c8 * 8) = v;
        }
#pragma unroll
        for (int i = 0; i < 8; ++i) {
            int c = tid + i * 256;
            *(uint4*)(Wl + c * 8) = *(const uint4*)(W2 + c * 8);
        }
        __syncthreads();
        f32x4 p[8];
#pragma unroll
        for (int c = 0; c < 8; ++c) p[c] = (f32x4){0.f, 0.f, 0.f, 0.f};
#pragma unroll
        for (int kt = 0; kt < 4; ++kt) {
            s16x8 a = *(const s16x8*)(Ad + (w * 16 + m) * 128 + kt * 32 + q * 8);
#pragma unroll
            for (int c = 0; c < 8; ++c) {
                s16x8 b = *(const s16x8*)(Wl + (c * 16 + m) * 128 + kt * 32 + q * 8);
                p[c] = __builtin_amdgcn_mfma_f32_16x16x32_bf16(a, b, p[c], 0, 0, 0);
            }
        }
        __syncthreads();
#pragma unroll
        for (int c = 0; c < 8; ++c) {
            int col = c * 16 + m;
            float bv = bias[col];
#pragma unroll
            for (int r = 0; r < 4; ++r)
                Ad[(w * 16 + q * 4 + r) * 128 + col] = f2b(p[c][r] + bv);
        }
#pragma unroll
        for (int i = 0; i < 8; ++i) {
            int c = tid + i * 256;
            int j = c >> 4, k8 = c & 15;
            *(uint4*)(Wl + j * 128 + k8 * 8) = *(const uint4*)(wm1t + (size_t)j * 256 + koff + k8 * 8);
        }
        __syncthreads();
#pragma unroll
        for (int kt = 0; kt < 4; ++kt) {
            s16x8 a = *(const s16x8*)(Ad + (w * 16 + m) * 128 + kt * 32 + q * 8);
#pragma unroll
            for (int c = 0; c < 8; ++c) {
                s16x8 b = *(const s16x8*)(Wl + (c * 16 + m) * 128 + kt * 32 + q * 8);
                acc[c] = __builtin_amdgcn_mfma_f32_16x16x32_bf16(a, b, acc[c], 0, 0, 0);
            }
        }
        __syncthreads();
    }
    // epilogue: write h1 (bf16) + per-block BN partials
    float s[8], s2[8];
#pragma unroll
    for (int c = 0; c < 8; ++c) {
        int col = c * 16 + m;
        s[c] = 0.f; s2[c] = 0.f;
#pragma unroll
        for (int r = 0; r < 4; ++r) {
            int row = row0 + w * 16 + q * 4 + r;
            unsigned short hb = f2b(acc[c][r]);
            float v = 0.f;
            if (row < NN) {
                h1[(size_t)row * DD + col] = hb;
                v = b2f((unsigned int)hb);
            }
            s[c] += v; s2[c] += v * v;
        }
    }
#pragma unroll
    for (int c = 0; c < 8; ++c) {
        s[c]  += __shfl_xor(s[c], 16, 64);  s[c]  += __shfl_xor(s[c], 32, 64);
        s2[c] += __shfl_xor(s2[c], 16, 64); s2[c] += __shfl_xor(s2[c], 32, 64);
    }
    float* fb = (float*)Ad;            // 4 waves x 128 cols sums, then sumsqs (4KB < 16KB)
    if (q == 0) {
#pragma unroll
        for (int c = 0; c < 8; ++c) {
            fb[w * 128 + c * 16 + m] = s[c];
            fb[512 + w * 128 + c * 16 + m] = s2[c];
        }
    }
    __syncthreads();
    int col = tid & 127;
    float* dst = bns + (blockIdx.x & 7) * 256;   // 8 contention-spread copies
    if (tid < 128)
        atomicAdd(&dst[col], fb[col] + fb[128 + col] + fb[256 + col] + fb[384 + col]);
    else
        atomicAdd(&dst[128 + col], fb[512 + col] + fb[640 + col] + fb[768 + col] + fb[896 + col]);
}

// ---------------- BN reduce+finalize (1 block) ----------------
__global__ void k_bnred(const float* __restrict__ bns,
                        const float* __restrict__ gamma, const float* __restrict__ beta,
                        float* __restrict__ bn) {
    int c = threadIdx.x;
    if (c >= 128) return;
    float s = 0.f, s2 = 0.f;
#pragma unroll
    for (int i = 0; i < 8; ++i) {
        s  += bns[i * 256 + c];
        s2 += bns[i * 256 + 128 + c];
    }
    const float inv = 1.0f / (float)NN;
    float mu = s * inv;
    float var = s2 * inv - mu * mu;
    float a = gamma[c] * rsqrtf(var + 1e-5f);
    bn[c] = a;
    bn[c + 128] = beta[c] - mu * a;
}

// ---------------- head (+ canary in last thread of last block) ----------------
__global__ void k_head(const unsigned short* __restrict__ h1, const float* __restrict__ bn,
                       const float* __restrict__ Wm2, float* __restrict__ out,
                       const int* __restrict__ deg, const unsigned short* __restrict__ hB) {
    int row = blockIdx.x * 4 + (threadIdx.x >> 6);
    int lane = threadIdx.x & 63;
    if (row < NN) {
        float h0 = b2f((unsigned int)h1[(size_t)row * DD + lane]);
        float h64 = b2f((unsigned int)h1[(size_t)row * DD + lane + 64]);
        float v0 = fmaxf(h0 * bn[lane] + bn[128 + lane], 0.f);
        float v1 = fmaxf(h64 * bn[lane + 64] + bn[128 + lane + 64], 0.f);
        float2 wa = *(const float2*)(Wm2 + lane * 2);
        float2 wb = *(const float2*)(Wm2 + (lane + 64) * 2);
        float acc0 = v0 * wa.x + v1 * wb.x;
        float acc1 = v0 * wa.y + v1 * wb.y;
#pragma unroll
        for (int off = 32; off > 0; off >>= 1) {
            acc0 += __shfl_down(acc0, off, 64);
            acc1 += __shfl_down(acc1, off, 64);
        }
        if (lane == 0) *(float2*)(out + (size_t)row * 2) = make_float2(acc0, acc1);
    }
    // canary (failure modes only; races with row0 writes only when stamping)
    if (blockIdx.x == 12499 && threadIdx.x == 255) {
        float sentinel = 0.f;
        int d = deg[NN + 1234];
        if (d < 0 || d > 100000) sentinel = 100.0f;
        else {
            float sa = 0.f;
            for (int j = 0; j < DD; ++j) sa += fabsf(b2f((unsigned int)hB[777 * DD + j]));
            if (!(sa > 0.f)) sentinel = 200.0f;
            else {
                float sc = 0.f;
                for (int j = 0; j < DD; ++j) sc += fabsf(b2f((unsigned int)h1[(size_t)444 * DD + j]));
                if (!(sc > 0.f)) sentinel = 400.0f;
            }
        }
        if (sentinel != 0.f) out[0] = sentinel;
    }
}

// ---------------- host-fail stamp ----------------
__global__ void k_fail(float* __restrict__ out, int code) {
    if (threadIdx.x == 0 && blockIdx.x == 0) out[0] = (float)code;
}

// ---------------- workspace layout (bytes) ----------------
static constexpr size_t O_DEG  = 0;           // 800000
static constexpr size_t O_ELL0 = 800000;      // 6.4M -> 7200000
static constexpr size_t O_ELL1 = 7200000;     // -> 13600000
static constexpr size_t O_H1   = 800000;      // 12.8M overlay (ells dead at fuse3)
static constexpr size_t O_XAS  = 13600000;    // 12.8M ; hA overlays
static constexpr size_t O_XBS  = 26400000;    // 12.8M ; hB overlays
static constexpr size_t O_AG0  = 39200000;    // 12.8M
static constexpr size_t O_AG1  = 52000000;    // 12.8M
static constexpr size_t O_WT   = 64800000;    // 196608
static constexpr size_t O_BNS  = 64996608;    // 8 copies x 256 f32 = 8192
static constexpr size_t O_BNAB = 65004800;    // 1024
static constexpr size_t O_END  = 65005824;

extern "C" void kernel_launch(void* const* d_in, const int* in_sizes, int n_in,
                              void* d_out, int out_size, void* d_ws, size_t ws_size,
                              hipStream_t stream) {
    const float* xA    = (const float*)d_in[0];
    const float* xB    = (const float*)d_in[1];
    const int* src0 = (const int*)d_in[2];
    const int* dst0 = (const int*)d_in[3];
    const int* src1 = (const int*)d_in[4];
    const int* dst1 = (const int*)d_in[5];
    const float* W1r0  = (const float*)d_in[6];
    const float* b1r0  = (const float*)d_in[7];
    const float* W1r1  = (const float*)d_in[8];
    const float* b1r1  = (const float*)d_in[9];
    const float* W2r0  = (const float*)d_in[10];
    const float* b2r0  = (const float*)d_in[11];
    const float* W2r1  = (const float*)d_in[12];
    const float* b2r1  = (const float*)d_in[13];
    const float* Wm1   = (const float*)d_in[14];
    const float* gamma = (const float*)d_in[15];
    const float* beta  = (const float*)d_in[16];
    const float* Wm2   = (const float*)d_in[17];

    char* ws = (char*)d_ws;
    int*   deg  = (int*)(ws + O_DEG);
    unsigned short* ell0 = (unsigned short*)(ws + O_ELL0);
    unsigned short* ell1 = (unsigned short*)(ws + O_ELL1);
    unsigned short* h1  = (unsigned short*)(ws + O_H1);    // overlay of ells
    unsigned short* xAs = (unsigned short*)(ws + O_XAS);
    unsigned short* hA  = (unsigned short*)(ws + O_XAS);   // overlay
    unsigned short* xBs = (unsigned short*)(ws + O_XBS);
    unsigned short* hB  = (unsigned short*)(ws + O_XBS);   // overlay
    unsigned short* ag0 = (unsigned short*)(ws + O_AG0);
    unsigned short* ag1 = (unsigned short*)(ws + O_AG1);
    unsigned short* wt  = (unsigned short*)(ws + O_WT);
    float* bns  = (float*)(ws + O_BNS);
    float* bnab = (float*)(ws + O_BNAB);
    float* out  = (float*)d_out;

    int hostFail = 0;
    if (ws_size < O_END) hostFail = 700;
    else if (n_in < 18) hostFail = 900;
    else if (in_sizes[0] != NN * DD) hostFail = 800;
    else if (in_sizes[2] != NE) hostFail = 850;

    if (hostFail) {
        k_fail<<<1, 64, 0, stream>>>(out, hostFail);
        return;
    }

    k_zero2<<<(200000 + 255) / 256, 256, 0, stream>>>(deg, 200000, (int*)bns, 2048);
    k_build<<<8 * 640, 256, 0, stream>>>(src0, dst0, src1, dst1, deg, ell0, ell1);
    k_prep<<<25384, 256, 0, stream>>>(xA, xB, deg, xAs, xBs, W1r0, W1r1, W2r0, W2r1, Wm1, wt);

    const int AB = 6250;              // 8 nodes/block
    const int GB = (NN + 63) / 64;    // 782

    // conv1
    k_agg2<<<dim3(AB, 2), 256, 0, stream>>>(xAs, xBs, ell0, ell1, deg + NN, deg + 3 * NN, ag0, ag1);
    k_gemm2<1,1,1><<<dim3(GB, 2), 256, 0, stream>>>(ag0, ag1, wt, wt + 16384, b1r0, b1r1,
                                                    deg + 2 * NN, deg, hB, hA, 128, 0, 0);
    // conv2 aggs (ells die after this)
    k_agg2<<<dim3(AB, 2), 256, 0, stream>>>(hA, hB, ell0, ell1, deg + NN, deg + 3 * NN, ag0, ag1);
    // fused conv2 gemms + MLP + BN partials
    k_fuse3<<<GB, 256, 0, stream>>>(ag0, ag1, wt + 32768, wt + 49152, b2r0, b2r1,
                                    wt + 65536, h1, bns);
    k_bnred<<<1, 128, 0, stream>>>(bns, gamma, beta, bnab);
    k_head<<<12500, 256, 0, stream>>>(h1, bnab, Wm2, out, deg, hB);
}